// Round 1
// baseline (444.807 us; speedup 1.0000x reference)
//
#include <hip/hip_runtime.h>
#include <cstdint>
#include <cstddef>

// ---------------------------------------------------------------------------
// CrossAttention on MI355X (gfx950), v1.
// Pipeline: f32->bf16 converts, weight transpose-converts, 3 proj GEMMs
// (V produced pre-transposed), flash attention, output GEMM (+bias, f32 out).
// All matmuls: mfma_f32_16x16x32_bf16, fp32 accumulate.
// ---------------------------------------------------------------------------

typedef __attribute__((ext_vector_type(8))) __bf16 bf16x8;
typedef __attribute__((ext_vector_type(4))) float  f32x4;

__device__ __forceinline__ unsigned short f2bf(float f) {
  union { float f; unsigned u; } v; v.f = f;
  unsigned r = v.u + 0x7FFFu + ((v.u >> 16) & 1u);   // RNE
  return (unsigned short)(r >> 16);
}

__device__ __forceinline__ void async_copy16(const void* g, void* l) {
  __builtin_amdgcn_global_load_lds(
      (const __attribute__((address_space(1))) void*)g,
      (__attribute__((address_space(3))) void*)l, 16, 0, 0);
}

// ---------------------------------------------------------------------------
// f32 -> bf16 elementwise (4 elems/thread/iter)
// ---------------------------------------------------------------------------
__global__ void convert_f32_bf16(const float* __restrict__ in,
                                 unsigned short* __restrict__ out, int n4) {
  int idx = blockIdx.x * blockDim.x + threadIdx.x;
  int stride = gridDim.x * blockDim.x;
  for (int i = idx; i < n4; i += stride) {
    float4 v = ((const float4*)in)[i];
    ushort4 o;
    o.x = f2bf(v.x); o.y = f2bf(v.y); o.z = f2bf(v.z); o.w = f2bf(v.w);
    ((ushort4*)out)[i] = o;
  }
}

// ---------------------------------------------------------------------------
// W [K][N] f32 -> Wt [N][K] bf16 (tiled transpose)
// ---------------------------------------------------------------------------
__global__ void tconv(const float* __restrict__ W,
                      unsigned short* __restrict__ Wt, int Kd, int Nd) {
  __shared__ float t[32][33];
  int tx = threadIdx.x, ty = threadIdx.y;  // 32 x 8
  int n0 = blockIdx.x * 32, k0 = blockIdx.y * 32;
#pragma unroll
  for (int i = 0; i < 4; ++i)
    t[ty + i * 8][tx] = W[(size_t)(k0 + ty + i * 8) * Nd + n0 + tx];
  __syncthreads();
#pragma unroll
  for (int i = 0; i < 4; ++i)
    Wt[(size_t)(n0 + ty + i * 8) * Kd + k0 + tx] = f2bf(t[tx][ty + i * 8]);
}

// ---------------------------------------------------------------------------
// GEMM: C[M,N] = A[M,K] * Bt[N,K]^T   (both bf16 row-major-in-their-layout)
// MODE 0: C bf16 [M][N]
// MODE 1: C f32  [M][N] + bias[col]
// MODE 2: C bf16 scattered to Vt layout: row i=h*128+d, col c=b*2048+j
//         -> off = ((b*8+h)<<18) + d*2048 + j
// 128x128 tile, BK=32, 4 waves (2x2), global_load_lds staging.
// ---------------------------------------------------------------------------
template <int MODE>
__global__ __launch_bounds__(256, 2) void gemm_bt(
    const unsigned short* __restrict__ A, const unsigned short* __restrict__ Bt,
    void* __restrict__ Cp, const float* __restrict__ bias, int M, int N, int Kd) {
  __shared__ __align__(16) unsigned short As[128 * 32];
  __shared__ __align__(16) unsigned short Bs[128 * 32];
  int tid = threadIdx.x, lane = tid & 63, wid = tid >> 6;
  int wm = wid >> 1, wn = wid & 1;
  int m0 = blockIdx.y * 128, n0 = blockIdx.x * 128;
  int l15 = lane & 15, g = lane >> 4;
  const unsigned short* Ag = A + (size_t)m0 * Kd;
  const unsigned short* Bg = Bt + (size_t)n0 * Kd;
  f32x4 acc[4][4] = {};

  for (int k0 = 0; k0 < Kd; k0 += 32) {
#pragma unroll
    for (int it = 0; it < 2; ++it) {
      int c = it * 256 + tid;       // 512 chunks of 16B per tile
      int row = c >> 2, kg = c & 3; // [128 rows][4 chunks]
      async_copy16(Ag + (size_t)row * Kd + k0 + kg * 8, &As[c * 8]);
      async_copy16(Bg + (size_t)row * Kd + k0 + kg * 8, &Bs[c * 8]);
    }
    __syncthreads();  // drains vmcnt before barrier (compiler-enforced)
    bf16x8 af[4], bfr[4];
#pragma unroll
    for (int i = 0; i < 4; ++i) {
      af[i]  = *(const bf16x8*)(&As[(wm * 64 + i * 16 + l15) * 32 + g * 8]);
      bfr[i] = *(const bf16x8*)(&Bs[(wn * 64 + i * 16 + l15) * 32 + g * 8]);
    }
#pragma unroll
    for (int i = 0; i < 4; ++i)
#pragma unroll
      for (int j = 0; j < 4; ++j)
        acc[i][j] = __builtin_amdgcn_mfma_f32_16x16x32_bf16(af[i], bfr[j], acc[i][j], 0, 0, 0);
    __syncthreads();
  }

  // Epilogue. D layout: col = lane&15, row = (lane>>4)*4 + r  (m89-verified)
#pragma unroll
  for (int i = 0; i < 4; ++i) {
#pragma unroll
    for (int j = 0; j < 4; ++j) {
#pragma unroll
      for (int r = 0; r < 4; ++r) {
        int row = m0 + wm * 64 + i * 16 + g * 4 + r;
        int col = n0 + wn * 64 + j * 16 + l15;
        float v = acc[i][j][r];
        if (MODE == 0) {
          ((unsigned short*)Cp)[(size_t)row * N + col] = f2bf(v);
        } else if (MODE == 1) {
          ((float*)Cp)[(size_t)row * N + col] = v + bias[col];
        } else {
          size_t off = ((size_t)((col >> 11) * 8 + (row >> 7)) << 18) +
                       (size_t)(row & 127) * 2048 + (size_t)(col & 2047);
          ((unsigned short*)Cp)[off] = f2bf(v);
        }
      }
    }
  }
}

// ---------------------------------------------------------------------------
// Flash attention. Q,K bf16 [B*Nk][1024] (head-major cols), Vt bf16 [32][128][2048].
// Block: 256 thr (4 waves), QBLK=64 (16 q-rows/wave), KVBLK=64.
// K tile [64][128] and Vt tile [128][64] staged with XOR swizzle
// (chunk ^= row&7, pre-swizzled global source; rule #21 both-sides).
// ---------------------------------------------------------------------------
#define KVB 64
#define NKV 2048

__global__ __launch_bounds__(256, 2) void attn_kernel(
    const unsigned short* __restrict__ Q, const unsigned short* __restrict__ K,
    const unsigned short* __restrict__ Vt, unsigned short* __restrict__ O) {
  __shared__ __align__(16) unsigned short Ks[KVB * 128];   // [j][k], swizzled
  __shared__ __align__(16) unsigned short Vs[128 * KVB];   // [d][j], swizzled
  __shared__ __align__(16) unsigned short Ps[4 * 16 * 72]; // per-wave P bounce, padded

  int tid = threadIdx.x, lane = tid & 63, w = tid >> 6;
  int l15 = lane & 15, g = lane >> 4;
  int bh = blockIdx.y, b = bh >> 3, h = bh & 7;
  int q0 = blockIdx.x * 64;

  const unsigned short* Qg = Q + ((size_t)(b * 2048 + q0 + w * 16)) * 1024 + h * 128;
  const unsigned short* Kg = K + ((size_t)(b * 2048)) * 1024 + h * 128;
  const unsigned short* Vg = Vt + (size_t)bh * (128 * 2048);

  // Q fragments live in registers all kernel: A[m=l15][k = kf*32 + g*8 + jj]
  bf16x8 qf[4];
#pragma unroll
  for (int kf = 0; kf < 4; ++kf)
    qf[kf] = *(const bf16x8*)(Qg + (size_t)l15 * 1024 + kf * 32 + g * 8);

  f32x4 of[8] = {};          // O acc: [df][r], q = g*4+r, d = df*16+l15
  float mrun[4], lrun[4];
#pragma unroll
  for (int r = 0; r < 4; ++r) { mrun[r] = -1e30f; lrun[r] = 0.f; }

  const float sc = 0.125f * 1.44269504f;  // scale * log2(e)

  for (int j0 = 0; j0 < NKV; j0 += KVB) {
    // ---- stage K tile: 64 rows x 16 chunks(16B); source chunk pre-swizzled
#pragma unroll
    for (int it = 0; it < 4; ++it) {
      int c = it * 256 + tid;
      int row = c >> 4, kc = c & 15;
      async_copy16(Kg + (size_t)(j0 + row) * 1024 + ((kc ^ (row & 7)) * 8), &Ks[c * 8]);
    }
    // ---- stage Vt tile: 128 rows x 8 chunks
#pragma unroll
    for (int it = 0; it < 4; ++it) {
      int c = it * 256 + tid;
      int row = c >> 3, jc = c & 7;
      async_copy16(Vg + (size_t)row * 2048 + j0 + ((jc ^ (row & 7)) * 8), &Vs[c * 8]);
    }
    __syncthreads();

    // ---- S = Q K^T : s[jf] covers j = jf*16 + l15 (D-cols), q = g*4+r (D-rows)
    f32x4 s[4] = {};
#pragma unroll
    for (int jf = 0; jf < 4; ++jf) {
      int j = jf * 16 + l15;
#pragma unroll
      for (int kf = 0; kf < 4; ++kf) {
        bf16x8 kfr = *(const bf16x8*)(&Ks[j * 128 + (((kf * 4 + g) ^ (j & 7)) * 8)]);
        s[jf] = __builtin_amdgcn_mfma_f32_16x16x32_bf16(qf[kf], kfr, s[jf], 0, 0, 0);
      }
    }

    // ---- online softmax (row = q = g*4+r; 16 lanes of same g hold the j's)
#pragma unroll
    for (int r = 0; r < 4; ++r) {
      float mx = fmaxf(fmaxf(s[0][r], s[1][r]), fmaxf(s[2][r], s[3][r]));
#pragma unroll
      for (int msk = 1; msk < 16; msk <<= 1) mx = fmaxf(mx, __shfl_xor(mx, msk, 64));
      float mnew = fmaxf(mrun[r], mx);
      float resc = __builtin_amdgcn_exp2f((mrun[r] - mnew) * sc);
      mrun[r] = mnew;
      float ps = 0.f;
      float pj[4];
#pragma unroll
      for (int jf = 0; jf < 4; ++jf) {
        pj[jf] = __builtin_amdgcn_exp2f((s[jf][r] - mnew) * sc);
        ps += pj[jf];
      }
#pragma unroll
      for (int msk = 1; msk < 16; msk <<= 1) ps += __shfl_xor(ps, msk, 64);
      lrun[r] = lrun[r] * resc + ps;
#pragma unroll
      for (int df = 0; df < 8; ++df) of[df][r] *= resc;
      // bounce P to LDS (D-layout -> A-layout), per-wave region, padded stride 72
#pragma unroll
      for (int jf = 0; jf < 4; ++jf)
        Ps[(w * 16 + g * 4 + r) * 72 + jf * 16 + l15] = f2bf(pj[jf]);
    }

    // ---- PV: O[q][d] += P[q][j] V[j][d];  A = P frags, B from Vs rows (contig j)
    bf16x8 pa[2];
#pragma unroll
    for (int kf2 = 0; kf2 < 2; ++kf2)
      pa[kf2] = *(const bf16x8*)(&Ps[(w * 16 + l15) * 72 + kf2 * 32 + g * 8]);
#pragma unroll
    for (int df = 0; df < 8; ++df) {
      int d = df * 16 + l15;
#pragma unroll
      for (int kf2 = 0; kf2 < 2; ++kf2) {
        bf16x8 vfr = *(const bf16x8*)(&Vs[d * 64 + (((kf2 * 4 + g) ^ (d & 7)) * 8)]);
        of[df] = __builtin_amdgcn_mfma_f32_16x16x32_bf16(pa[kf2], vfr, of[df], 0, 0, 0);
      }
    }
    __syncthreads();
  }

  // ---- epilogue: O /= l, write bf16 [B*Nq][1024]
  float inv[4];
#pragma unroll
  for (int r = 0; r < 4; ++r) inv[r] = 1.0f / lrun[r];
  unsigned short* Og = O + ((size_t)(b * 2048 + q0 + w * 16)) * 1024 + h * 128;
#pragma unroll
  for (int df = 0; df < 8; ++df)
#pragma unroll
    for (int r = 0; r < 4; ++r)
      Og[(size_t)(g * 4 + r) * 1024 + df * 16 + l15] = f2bf(of[df][r] * inv[r]);
}

// ---------------------------------------------------------------------------
// Host side
// ---------------------------------------------------------------------------
extern "C" void kernel_launch(void* const* d_in, const int* in_sizes, int n_in,
                              void* d_out, int out_size, void* d_ws, size_t ws_size,
                              hipStream_t stream) {
  const float* x    = (const float*)d_in[0];
  const float* cond = (const float*)d_in[1];
  const float* Wq   = (const float*)d_in[2];
  const float* Wk   = (const float*)d_in[3];
  const float* Wv   = (const float*)d_in[4];
  const float* Wo   = (const float*)d_in[5];
  const float* bo   = (const float*)d_in[6];

  char* p = (char*)d_ws;
  unsigned short* xb  = (unsigned short*)(p + 0);          // 16 MB  x bf16
  unsigned short* cb  = (unsigned short*)(p + 16777216);   // 16 MB  cond bf16
  unsigned short* Wqt = (unsigned short*)(p + 33554432);   // 2 MB   [N][K]
  unsigned short* Wkt = (unsigned short*)(p + 35651584);
  unsigned short* Wvt = (unsigned short*)(p + 37748736);
  unsigned short* Wot = (unsigned short*)(p + 39845888);
  unsigned short* Qb  = (unsigned short*)(p + 41943040);   // 16 MB [8192][1024]
  unsigned short* Kb  = (unsigned short*)(p + 58720256);   // 16 MB
  unsigned short* Vtb = (unsigned short*)(p + 75497472);   // 16 MB [32][128][2048]
  unsigned short* Ab  = (unsigned short*)(p + 92274688);   // 16 MB attn out
  (void)in_sizes; (void)n_in; (void)out_size; (void)ws_size;

  // converts
  convert_f32_bf16<<<2048, 256, 0, stream>>>(x, xb, 8388608 / 4);
  convert_f32_bf16<<<2048, 256, 0, stream>>>(cond, cb, 8388608 / 4);
  tconv<<<dim3(32, 32), dim3(32, 8), 0, stream>>>(Wq, Wqt, 1024, 1024);
  tconv<<<dim3(32, 32), dim3(32, 8), 0, stream>>>(Wk, Wkt, 1024, 1024);
  tconv<<<dim3(32, 32), dim3(32, 8), 0, stream>>>(Wv, Wvt, 1024, 1024);
  tconv<<<dim3(32, 32), dim3(32, 8), 0, stream>>>(Wo, Wot, 1024, 1024);

  // projections: Q = xb*Wqt^T, K = cb*Wkt^T  (grid: x=N/128, y=M/128)
  gemm_bt<0><<<dim3(8, 64), 256, 0, stream>>>(xb, Wqt, Qb, nullptr, 8192, 1024, 1024);
  gemm_bt<0><<<dim3(8, 64), 256, 0, stream>>>(cb, Wkt, Kb, nullptr, 8192, 1024, 1024);
  // V transposed at source: Vt[i=h*128+d][c=b*2048+j] = Wvt[i,:] . cb[c,:]
  gemm_bt<2><<<dim3(64, 8), 256, 0, stream>>>(Wvt, cb, Vtb, nullptr, 1024, 8192, 1024);

  // flash attention: grid (Nq/64, B*H)
  attn_kernel<<<dim3(32, 32), 256, 0, stream>>>(Qb, Kb, Vtb, Ab);

  // output projection + bias, f32 out
  gemm_bt<1><<<dim3(8, 64), 256, 0, stream>>>(Ab, Wot, (float*)d_out, bo, 8192, 1024, 1024);
}

// Round 2
// 418.927 us; speedup vs baseline: 1.0618x; 1.0618x over previous
//
#include <hip/hip_runtime.h>
#include <cstdint>
#include <cstddef>

// ---------------------------------------------------------------------------
// CrossAttention on MI355X (gfx950), v2.
// v1 -> v2: T3-minimum 2-phase prefetch (dbuf LDS, counted-drain AFTER compute,
// raw s_barrier with sched_barrier fences) in GEMM + attention; attention
// widened to 8 waves / QBLK=128; defer-max (T13); setprio on attn MFMA (T5);
// XCD-chunked swizzle on GEMMs (T1).
// ---------------------------------------------------------------------------

typedef __attribute__((ext_vector_type(8))) __bf16 bf16x8;
typedef __attribute__((ext_vector_type(4))) float  f32x4;

__device__ __forceinline__ unsigned short f2bf(float f) {
  union { float f; unsigned u; } v; v.f = f;
  unsigned r = v.u + 0x7FFFu + ((v.u >> 16) & 1u);   // RNE
  return (unsigned short)(r >> 16);
}

__device__ __forceinline__ void async_copy16(const void* g, void* l) {
  __builtin_amdgcn_global_load_lds(
      (const __attribute__((address_space(1))) void*)g,
      (__attribute__((address_space(3))) void*)l, 16, 0, 0);
}

__device__ __forceinline__ void fence_drain_barrier() {
  __builtin_amdgcn_sched_barrier(0);
  asm volatile("s_waitcnt vmcnt(0)" ::: "memory");
  __builtin_amdgcn_s_barrier();
  __builtin_amdgcn_sched_barrier(0);
}

// ---------------------------------------------------------------------------
// f32 -> bf16 elementwise
// ---------------------------------------------------------------------------
__global__ void convert_f32_bf16(const float* __restrict__ in,
                                 unsigned short* __restrict__ out, int n4) {
  int idx = blockIdx.x * blockDim.x + threadIdx.x;
  int stride = gridDim.x * blockDim.x;
  for (int i = idx; i < n4; i += stride) {
    float4 v = ((const float4*)in)[i];
    ushort4 o;
    o.x = f2bf(v.x); o.y = f2bf(v.y); o.z = f2bf(v.z); o.w = f2bf(v.w);
    ((ushort4*)out)[i] = o;
  }
}

// ---------------------------------------------------------------------------
// W [K][N] f32 -> Wt [N][K] bf16 (tiled transpose)
// ---------------------------------------------------------------------------
__global__ void tconv(const float* __restrict__ W,
                      unsigned short* __restrict__ Wt, int Kd, int Nd) {
  __shared__ float t[32][33];
  int tx = threadIdx.x, ty = threadIdx.y;  // 32 x 8
  int n0 = blockIdx.x * 32, k0 = blockIdx.y * 32;
#pragma unroll
  for (int i = 0; i < 4; ++i)
    t[ty + i * 8][tx] = W[(size_t)(k0 + ty + i * 8) * Nd + n0 + tx];
  __syncthreads();
#pragma unroll
  for (int i = 0; i < 4; ++i)
    Wt[(size_t)(n0 + ty + i * 8) * Kd + k0 + tx] = f2bf(t[tx][ty + i * 8]);
}

// ---------------------------------------------------------------------------
// GEMM: C[M,N] = A[M,K] * Bt[N,K]^T. 128x128 tile, BK=32, 4 waves,
// 2-phase prefetch dbuf (T3-min), XCD-chunked blockIdx swizzle (T1).
// MODE 0: C bf16 [M][N]
// MODE 1: C f32  [M][N] + bias[col]
// MODE 2: C bf16 scattered to Vt layout (row i=h*128+d, col c=b*2048+j)
// ---------------------------------------------------------------------------
template <int MODE>
__global__ __launch_bounds__(256, 2) void gemm_bt(
    const unsigned short* __restrict__ A, const unsigned short* __restrict__ Bt,
    void* __restrict__ Cp, const float* __restrict__ bias, int M, int N, int Kd) {
  __shared__ __align__(16) unsigned short As[2][128 * 32];
  __shared__ __align__(16) unsigned short Bs[2][128 * 32];
  int tid = threadIdx.x, lane = tid & 63, wid = tid >> 6;
  int wm = wid >> 1, wn = wid & 1;
  // T1: XCD-chunked swizzle (nwg is 512 or 1024 -> %8==0, bijective)
  int nwg = gridDim.x * gridDim.y;
  int wg = blockIdx.y * gridDim.x + blockIdx.x;
  int cpx = nwg >> 3;
  int sw = (wg & 7) * cpx + (wg >> 3);
  int bx = sw % gridDim.x, by = sw / gridDim.x;
  int m0 = by * 128, n0 = bx * 128;
  int l15 = lane & 15, g = lane >> 4;
  const unsigned short* Ag = A + (size_t)m0 * Kd;
  const unsigned short* Bg = Bt + (size_t)n0 * Kd;
  f32x4 acc[4][4] = {};

  auto stage = [&](int buf, int k0) {
#pragma unroll
    for (int it = 0; it < 2; ++it) {
      int c = it * 256 + tid;       // 512 chunks of 16B per tile
      int row = c >> 2, kg = c & 3; // [128 rows][4 chunks]
      async_copy16(Ag + (size_t)row * Kd + k0 + kg * 8, &As[buf][c * 8]);
      async_copy16(Bg + (size_t)row * Kd + k0 + kg * 8, &Bs[buf][c * 8]);
    }
  };

  stage(0, 0);
  fence_drain_barrier();

  const int NT = Kd >> 5;
  int cur = 0;
  for (int t = 0; t < NT; ++t) {
    if (t + 1 < NT) stage(cur ^ 1, (t + 1) * 32);   // prefetch next K-tile
    bf16x8 af[4], bfr[4];
#pragma unroll
    for (int i = 0; i < 4; ++i) {
      af[i]  = *(const bf16x8*)(&As[cur][(wm * 64 + i * 16 + l15) * 32 + g * 8]);
      bfr[i] = *(const bf16x8*)(&Bs[cur][(wn * 64 + i * 16 + l15) * 32 + g * 8]);
    }
#pragma unroll
    for (int i = 0; i < 4; ++i)
#pragma unroll
      for (int j = 0; j < 4; ++j)
        acc[i][j] = __builtin_amdgcn_mfma_f32_16x16x32_bf16(af[i], bfr[j], acc[i][j], 0, 0, 0);
    fence_drain_barrier();   // prefetch (overlapped with MFMA) lands here
    cur ^= 1;
  }

  // Epilogue. D layout: col = lane&15, row = (lane>>4)*4 + r
#pragma unroll
  for (int i = 0; i < 4; ++i) {
#pragma unroll
    for (int j = 0; j < 4; ++j) {
#pragma unroll
      for (int r = 0; r < 4; ++r) {
        int row = m0 + wm * 64 + i * 16 + g * 4 + r;
        int col = n0 + wn * 64 + j * 16 + l15;
        float v = acc[i][j][r];
        if (MODE == 0) {
          ((unsigned short*)Cp)[(size_t)row * N + col] = f2bf(v);
        } else if (MODE == 1) {
          ((float*)Cp)[(size_t)row * N + col] = v + bias[col];
        } else {
          size_t off = ((size_t)((col >> 11) * 8 + (row >> 7)) << 18) +
                       (size_t)(row & 127) * 2048 + (size_t)(col & 2047);
          ((unsigned short*)Cp)[off] = f2bf(v);
        }
      }
    }
  }
}

// ---------------------------------------------------------------------------
// Flash attention v2. 512 thr (8 waves), QBLK=128 (16 q-rows/wave), KVB=64,
// double-buffered K/V staging with prefetch; XOR-swizzled tiles; defer-max.
// Q,K bf16 [B*Nk][1024] (head-major cols), Vt bf16 [32][128][2048].
// ---------------------------------------------------------------------------
#define KVB 64
#define NKV 2048

__global__ __launch_bounds__(512, 1) void attn_kernel(
    const unsigned short* __restrict__ Q, const unsigned short* __restrict__ K,
    const unsigned short* __restrict__ Vt, unsigned short* __restrict__ O) {
  __shared__ __align__(16) unsigned short Ks[2][KVB * 128];   // [j][k], swizzled
  __shared__ __align__(16) unsigned short Vs[2][128 * KVB];   // [d][j], swizzled
  __shared__ __align__(16) unsigned short Ps[8 * 16 * 72];    // per-wave P bounce

  int tid = threadIdx.x, lane = tid & 63, w = tid >> 6;
  int l15 = lane & 15, g = lane >> 4;
  int bh = blockIdx.y, b = bh >> 3, h = bh & 7;
  int q0 = blockIdx.x * 128;

  const unsigned short* Qg = Q + ((size_t)(b * 2048 + q0 + w * 16)) * 1024 + h * 128;
  const unsigned short* Kg = K + ((size_t)(b * 2048)) * 1024 + h * 128;
  const unsigned short* Vg = Vt + (size_t)bh * (128 * 2048);

  // Q fragments in registers all kernel: A[m=l15][k = kf*32 + g*8 + jj]
  bf16x8 qf[4];
#pragma unroll
  for (int kf = 0; kf < 4; ++kf)
    qf[kf] = *(const bf16x8*)(Qg + (size_t)l15 * 1024 + kf * 32 + g * 8);

  f32x4 of[8] = {};          // O acc: [df][r], q = g*4+r, d = df*16+l15
  float mrun[4], lrun[4];
#pragma unroll
  for (int r = 0; r < 4; ++r) { mrun[r] = -1e30f; lrun[r] = 0.f; }

  auto stage = [&](int buf, int j0) {
#pragma unroll
    for (int it = 0; it < 2; ++it) {          // K tile: 1024 chunks
      int c = it * 512 + tid;
      int row = c >> 4, kc = c & 15;
      async_copy16(Kg + (size_t)(j0 + row) * 1024 + ((kc ^ (row & 7)) * 8),
                   &Ks[buf][c * 8]);
    }
#pragma unroll
    for (int it = 0; it < 2; ++it) {          // V tile: 1024 chunks
      int c = it * 512 + tid;
      int row = c >> 3, jc = c & 7;
      async_copy16(Vg + (size_t)row * 2048 + j0 + ((jc ^ (row & 7)) * 8),
                   &Vs[buf][c * 8]);
    }
  };

  stage(0, 0);
  fence_drain_barrier();

  const float sc = 0.125f * 1.44269504f;  // scale * log2(e)
  int cur = 0;

  for (int t = 0; t < NKV / KVB; ++t) {
    if (t + 1 < NKV / KVB) stage(cur ^ 1, (t + 1) * KVB);  // prefetch next tile

    // ---- S = Q K^T : s[jf] covers j = jf*16 + l15, q = g*4+r
    f32x4 s[4] = {};
    __builtin_amdgcn_s_setprio(1);
#pragma unroll
    for (int jf = 0; jf < 4; ++jf) {
      int j = jf * 16 + l15;
#pragma unroll
      for (int kf = 0; kf < 4; ++kf) {
        bf16x8 kfr = *(const bf16x8*)(&Ks[cur][j * 128 + (((kf * 4 + g) ^ (j & 7)) * 8)]);
        s[jf] = __builtin_amdgcn_mfma_f32_16x16x32_bf16(qf[kf], kfr, s[jf], 0, 0, 0);
      }
    }
    __builtin_amdgcn_s_setprio(0);

    // ---- online softmax with defer-max (T13, THR=8 pre-scale -> P <= e)
#pragma unroll
    for (int r = 0; r < 4; ++r) {
      float mx = fmaxf(fmaxf(s[0][r], s[1][r]), fmaxf(s[2][r], s[3][r]));
#pragma unroll
      for (int msk = 1; msk < 16; msk <<= 1) mx = fmaxf(mx, __shfl_xor(mx, msk, 64));
      if (!__all(mx <= mrun[r] + 8.0f)) {
        float mnew = fmaxf(mrun[r], mx);
        float resc = __builtin_amdgcn_exp2f((mrun[r] - mnew) * sc);
        lrun[r] *= resc;
#pragma unroll
        for (int df = 0; df < 8; ++df) of[df][r] *= resc;
        mrun[r] = mnew;
      }
      float ps = 0.f;
      float pj[4];
#pragma unroll
      for (int jf = 0; jf < 4; ++jf) {
        pj[jf] = __builtin_amdgcn_exp2f((s[jf][r] - mrun[r]) * sc);
        ps += pj[jf];
      }
#pragma unroll
      for (int msk = 1; msk < 16; msk <<= 1) ps += __shfl_xor(ps, msk, 64);
      lrun[r] += ps;
      // bounce P to LDS (D-layout -> A-layout), per-wave region, stride 72
#pragma unroll
      for (int jf = 0; jf < 4; ++jf)
        Ps[(w * 16 + g * 4 + r) * 72 + jf * 16 + l15] = f2bf(pj[jf]);
    }

    // ---- PV: O[q][d] += P[q][j] V[j][d]
    bf16x8 pa[2];
#pragma unroll
    for (int kf2 = 0; kf2 < 2; ++kf2)
      pa[kf2] = *(const bf16x8*)(&Ps[(w * 16 + l15) * 72 + kf2 * 32 + g * 8]);
    __builtin_amdgcn_s_setprio(1);
#pragma unroll
    for (int df = 0; df < 8; ++df) {
      int d = df * 16 + l15;
#pragma unroll
      for (int kf2 = 0; kf2 < 2; ++kf2) {
        bf16x8 vfr = *(const bf16x8*)(&Vs[cur][d * 64 + (((kf2 * 4 + g) ^ (d & 7)) * 8)]);
        of[df] = __builtin_amdgcn_mfma_f32_16x16x32_bf16(pa[kf2], vfr, of[df], 0, 0, 0);
      }
    }
    __builtin_amdgcn_s_setprio(0);

    fence_drain_barrier();   // prefetch (overlapped with compute) lands here
    cur ^= 1;
  }

  // ---- epilogue: O /= l, write bf16 [B*Nq][1024]
  float inv[4];
#pragma unroll
  for (int r = 0; r < 4; ++r) inv[r] = 1.0f / lrun[r];
  unsigned short* Og = O + ((size_t)(b * 2048 + q0 + w * 16)) * 1024 + h * 128;
#pragma unroll
  for (int df = 0; df < 8; ++df)
#pragma unroll
    for (int r = 0; r < 4; ++r)
      Og[(size_t)(g * 4 + r) * 1024 + df * 16 + l15] = f2bf(of[df][r] * inv[r]);
}

// ---------------------------------------------------------------------------
// Host side
// ---------------------------------------------------------------------------
extern "C" void kernel_launch(void* const* d_in, const int* in_sizes, int n_in,
                              void* d_out, int out_size, void* d_ws, size_t ws_size,
                              hipStream_t stream) {
  const float* x    = (const float*)d_in[0];
  const float* cond = (const float*)d_in[1];
  const float* Wq   = (const float*)d_in[2];
  const float* Wk   = (const float*)d_in[3];
  const float* Wv   = (const float*)d_in[4];
  const float* Wo   = (const float*)d_in[5];
  const float* bo   = (const float*)d_in[6];

  char* p = (char*)d_ws;
  unsigned short* xb  = (unsigned short*)(p + 0);          // 16 MB  x bf16
  unsigned short* cb  = (unsigned short*)(p + 16777216);   // 16 MB  cond bf16
  unsigned short* Wqt = (unsigned short*)(p + 33554432);   // 2 MB   [N][K]
  unsigned short* Wkt = (unsigned short*)(p + 35651584);
  unsigned short* Wvt = (unsigned short*)(p + 37748736);
  unsigned short* Wot = (unsigned short*)(p + 39845888);
  unsigned short* Qb  = (unsigned short*)(p + 41943040);   // 16 MB [8192][1024]
  unsigned short* Kb  = (unsigned short*)(p + 58720256);   // 16 MB
  unsigned short* Vtb = (unsigned short*)(p + 75497472);   // 16 MB [32][128][2048]
  unsigned short* Ab  = (unsigned short*)(p + 92274688);   // 16 MB attn out
  (void)in_sizes; (void)n_in; (void)out_size; (void)ws_size;

  // converts
  convert_f32_bf16<<<2048, 256, 0, stream>>>(x, xb, 8388608 / 4);
  convert_f32_bf16<<<2048, 256, 0, stream>>>(cond, cb, 8388608 / 4);
  tconv<<<dim3(32, 32), dim3(32, 8), 0, stream>>>(Wq, Wqt, 1024, 1024);
  tconv<<<dim3(32, 32), dim3(32, 8), 0, stream>>>(Wk, Wkt, 1024, 1024);
  tconv<<<dim3(32, 32), dim3(32, 8), 0, stream>>>(Wv, Wvt, 1024, 1024);
  tconv<<<dim3(32, 32), dim3(32, 8), 0, stream>>>(Wo, Wot, 1024, 1024);

  // projections
  gemm_bt<0><<<dim3(8, 64), 256, 0, stream>>>(xb, Wqt, Qb, nullptr, 8192, 1024, 1024);
  gemm_bt<0><<<dim3(8, 64), 256, 0, stream>>>(cb, Wkt, Kb, nullptr, 8192, 1024, 1024);
  // V transposed at source: Vt[i=h*128+d][c=b*2048+j] = Wvt[i,:] . cb[c,:]
  gemm_bt<2><<<dim3(64, 8), 256, 0, stream>>>(Wvt, cb, Vtb, nullptr, 1024, 8192, 1024);

  // flash attention: grid (Nq/128, B*H)
  attn_kernel<<<dim3(16, 32), 512, 0, stream>>>(Qb, Kb, Vtb, Ab);

  // output projection + bias, f32 out
  gemm_bt<1><<<dim3(8, 64), 256, 0, stream>>>(Ab, Wot, (float*)d_out, bo, 8192, 1024, 1024);
}

// Round 4
// 398.142 us; speedup vs baseline: 1.1172x; 1.0522x over previous
//
#include <hip/hip_runtime.h>
#include <cstdint>
#include <cstddef>

// ---------------------------------------------------------------------------
// CrossAttention on MI355X (gfx950), v3 (resubmit — R3 bench was an
// infrastructure failure, kernel never measured).
// v2 -> v3: ring-4 LDS staging with prefetch distance 3 and counted
// s_waitcnt vmcnt(8) (never 0 in steady state) in GEMM AND attention;
// XCD-chunked block swizzle for attention KV L2 locality; scale folded into
// Q projection; lane-partial softmax denominator (epilogue reduce).
// ---------------------------------------------------------------------------

typedef __attribute__((ext_vector_type(8))) __bf16 bf16x8;
typedef __attribute__((ext_vector_type(4))) float  f32x4;

__device__ __forceinline__ unsigned short f2bf(float f) {
  union { float f; unsigned u; } v; v.f = f;
  unsigned r = v.u + 0x7FFFu + ((v.u >> 16) & 1u);   // RNE
  return (unsigned short)(r >> 16);
}

__device__ __forceinline__ void async_copy16(const void* g, void* l) {
  __builtin_amdgcn_global_load_lds(
      (const __attribute__((address_space(1))) void*)g,
      (__attribute__((address_space(3))) void*)l, 16, 0, 0);
}

// Wait for tile-t's staging (ring-4, 4 loads/thread/stage), then barrier.
// Steady state keeps 8 loads (2 future stages) in flight across the barrier.
__device__ __forceinline__ void wait_tile_barrier(int t, int NT) {
  __builtin_amdgcn_sched_barrier(0);
  if (t < NT - 2)       asm volatile("s_waitcnt vmcnt(8)" ::: "memory");
  else if (t == NT - 2) asm volatile("s_waitcnt vmcnt(4)" ::: "memory");
  else                  asm volatile("s_waitcnt vmcnt(0)" ::: "memory");
  __builtin_amdgcn_s_barrier();
  __builtin_amdgcn_sched_barrier(0);
}

// ---------------------------------------------------------------------------
// f32 -> bf16 elementwise
// ---------------------------------------------------------------------------
__global__ void convert_f32_bf16(const float* __restrict__ in,
                                 unsigned short* __restrict__ out, int n4) {
  int idx = blockIdx.x * blockDim.x + threadIdx.x;
  int stride = gridDim.x * blockDim.x;
  for (int i = idx; i < n4; i += stride) {
    float4 v = ((const float4*)in)[i];
    ushort4 o;
    o.x = f2bf(v.x); o.y = f2bf(v.y); o.z = f2bf(v.z); o.w = f2bf(v.w);
    ((ushort4*)out)[i] = o;
  }
}

// ---------------------------------------------------------------------------
// W [K][N] f32 -> Wt [N][K] bf16 (tiled transpose)
// ---------------------------------------------------------------------------
__global__ void tconv(const float* __restrict__ W,
                      unsigned short* __restrict__ Wt, int Kd, int Nd) {
  __shared__ float t[32][33];
  int tx = threadIdx.x, ty = threadIdx.y;  // 32 x 8
  int n0 = blockIdx.x * 32, k0 = blockIdx.y * 32;
#pragma unroll
  for (int i = 0; i < 4; ++i)
    t[ty + i * 8][tx] = W[(size_t)(k0 + ty + i * 8) * Nd + n0 + tx];
  __syncthreads();
#pragma unroll
  for (int i = 0; i < 4; ++i)
    Wt[(size_t)(n0 + ty + i * 8) * Kd + k0 + tx] = f2bf(t[tx][ty + i * 8]);
}

// ---------------------------------------------------------------------------
// GEMM: C[M,N] = A[M,K] * Bt[N,K]^T. 128x128 tile, BK=32, 4 waves,
// ring-4 staging + counted vmcnt (T4), XCD-chunked swizzle (T1).
// MODE 0: C bf16 [M][N], scaled by oscale
// MODE 1: C f32  [M][N] + bias[col]
// MODE 2: C bf16 scattered to Vt layout (row i=h*128+d, col c=b*2048+j)
// ---------------------------------------------------------------------------
template <int MODE>
__global__ __launch_bounds__(256, 2) void gemm_bt(
    const unsigned short* __restrict__ A, const unsigned short* __restrict__ Bt,
    void* __restrict__ Cp, const float* __restrict__ bias, int M, int N, int Kd,
    float oscale) {
  __shared__ __align__(16) unsigned short As[4][128 * 32];
  __shared__ __align__(16) unsigned short Bs[4][128 * 32];
  int tid = threadIdx.x, lane = tid & 63, wid = tid >> 6;
  int wm = wid >> 1, wn = wid & 1;
  // T1: XCD-chunked swizzle (nwg 512/1024, %8==0 -> bijective)
  int nwg = gridDim.x * gridDim.y;
  int wg = blockIdx.y * gridDim.x + blockIdx.x;
  int cpx = nwg >> 3;
  int sw = (wg & 7) * cpx + (wg >> 3);
  int bx = sw % gridDim.x, by = sw / gridDim.x;
  int m0 = by * 128, n0 = bx * 128;
  int l15 = lane & 15, g = lane >> 4;
  const unsigned short* Ag = A + (size_t)m0 * Kd;
  const unsigned short* Bg = Bt + (size_t)n0 * Kd;
  f32x4 acc[4][4] = {};

  auto stage = [&](int buf, int k0) {   // 4 loads/thread
#pragma unroll
    for (int it = 0; it < 2; ++it) {
      int c = it * 256 + tid;       // 512 chunks of 16B per tile
      int row = c >> 2, kg = c & 3; // [128 rows][4 chunks]
      async_copy16(Ag + (size_t)row * Kd + k0 + kg * 8, &As[buf][c * 8]);
      async_copy16(Bg + (size_t)row * Kd + k0 + kg * 8, &Bs[buf][c * 8]);
    }
  };

  const int NT = Kd >> 5;           // 32
  stage(0, 0); stage(1, 32); stage(2, 64);

  for (int t = 0; t < NT; ++t) {
    wait_tile_barrier(t, NT);                       // tile t ready, buf t-1 free
    if (t + 3 < NT) stage((t + 3) & 3, (t + 3) * 32);
    int cur = t & 3;
    bf16x8 af[4], bfr[4];
#pragma unroll
    for (int i = 0; i < 4; ++i) {
      af[i]  = *(const bf16x8*)(&As[cur][(wm * 64 + i * 16 + l15) * 32 + g * 8]);
      bfr[i] = *(const bf16x8*)(&Bs[cur][(wn * 64 + i * 16 + l15) * 32 + g * 8]);
    }
    __builtin_amdgcn_s_setprio(1);
#pragma unroll
    for (int i = 0; i < 4; ++i)
#pragma unroll
      for (int j = 0; j < 4; ++j)
        acc[i][j] = __builtin_amdgcn_mfma_f32_16x16x32_bf16(af[i], bfr[j], acc[i][j], 0, 0, 0);
    __builtin_amdgcn_s_setprio(0);
  }

  // Epilogue. D layout: col = lane&15, row = (lane>>4)*4 + r
#pragma unroll
  for (int i = 0; i < 4; ++i) {
#pragma unroll
    for (int j = 0; j < 4; ++j) {
#pragma unroll
      for (int r = 0; r < 4; ++r) {
        int row = m0 + wm * 64 + i * 16 + g * 4 + r;
        int col = n0 + wn * 64 + j * 16 + l15;
        float v = acc[i][j][r];
        if (MODE == 0) {
          ((unsigned short*)Cp)[(size_t)row * N + col] = f2bf(v * oscale);
        } else if (MODE == 1) {
          ((float*)Cp)[(size_t)row * N + col] = v + bias[col];
        } else {
          size_t off = ((size_t)((col >> 11) * 8 + (row >> 7)) << 18) +
                       (size_t)(row & 127) * 2048 + (size_t)(col & 2047);
          ((unsigned short*)Cp)[off] = f2bf(v);
        }
      }
    }
  }
}

// ---------------------------------------------------------------------------
// Flash attention v3. 512 thr (8 waves), QBLK=128 (16 q-rows/wave), KVB=64,
// ring-4 K/V staging with prefetch distance 3 + counted vmcnt; XCD-chunked
// block swizzle (same-XCD blocks share bh -> KV L2-resident); XOR-swizzled
// tiles; defer-max; Q pre-scaled (exp2 domain).
// Q,K bf16 [B*Nk][1024] (head-major cols), Vt bf16 [32][128][2048].
// ---------------------------------------------------------------------------
#define KVB 64
#define NKV 2048

__global__ __launch_bounds__(512, 1) void attn_kernel(
    const unsigned short* __restrict__ Q, const unsigned short* __restrict__ K,
    const unsigned short* __restrict__ Vt, unsigned short* __restrict__ O) {
  __shared__ __align__(16) unsigned short Ks[4][KVB * 128];   // [j][k], swizzled
  __shared__ __align__(16) unsigned short Vs[4][128 * KVB];   // [d][j], swizzled
  __shared__ __align__(16) unsigned short Ps[8 * 16 * 72];    // per-wave P bounce

  int tid = threadIdx.x, lane = tid & 63, w = tid >> 6;
  int l15 = lane & 15, g = lane >> 4;
  // XCD-chunked swizzle: blocks with same (wgl%8) -> same XCD, contiguous sw
  // range -> 4 consecutive bh per XCD -> KV stays in that XCD's L2.
  int wgl = blockIdx.y * gridDim.x + blockIdx.x;   // 0..511
  int sw = (wgl & 7) * 64 + (wgl >> 3);
  int bh = sw >> 4, b = bh >> 3, h = bh & 7;
  int q0 = (sw & 15) * 128;

  const unsigned short* Qg = Q + ((size_t)(b * 2048 + q0 + w * 16)) * 1024 + h * 128;
  const unsigned short* Kg = K + ((size_t)(b * 2048)) * 1024 + h * 128;
  const unsigned short* Vg = Vt + (size_t)bh * (128 * 2048);

  // Q fragments in registers all kernel (Q pre-scaled by 0.125*log2e)
  bf16x8 qf[4];
#pragma unroll
  for (int kf = 0; kf < 4; ++kf)
    qf[kf] = *(const bf16x8*)(Qg + (size_t)l15 * 1024 + kf * 32 + g * 8);

  f32x4 of[8] = {};          // O acc: [df][r], q = g*4+r, d = df*16+l15
  float mrun[4], lrun[4];    // lrun is LANE-PARTIAL (reduced at epilogue)
#pragma unroll
  for (int r = 0; r < 4; ++r) { mrun[r] = -1e30f; lrun[r] = 0.f; }

  auto stage = [&](int buf, int j0) {   // 4 loads/thread
#pragma unroll
    for (int it = 0; it < 2; ++it) {          // K tile: 1024 chunks
      int c = it * 512 + tid;
      int row = c >> 4, kc = c & 15;
      async_copy16(Kg + (size_t)(j0 + row) * 1024 + ((kc ^ (row & 7)) * 8),
                   &Ks[buf][c * 8]);
    }
#pragma unroll
    for (int it = 0; it < 2; ++it) {          // V tile: 1024 chunks
      int c = it * 512 + tid;
      int row = c >> 3, jc = c & 7;
      async_copy16(Vg + (size_t)row * 2048 + j0 + ((jc ^ (row & 7)) * 8),
                   &Vs[buf][c * 8]);
    }
  };

  const int NT = NKV / KVB;   // 32
  stage(0, 0); stage(1, KVB); stage(2, 2 * KVB);

  for (int t = 0; t < NT; ++t) {
    wait_tile_barrier(t, NT);                         // tile t ready, buf t-1 free
    if (t + 3 < NT) stage((t + 3) & 3, (t + 3) * KVB);
    int cur = t & 3;

    // ---- S = Q K^T : s[jf] covers j = jf*16 + l15, q = g*4+r  (exp2 domain)
    f32x4 s[4] = {};
    __builtin_amdgcn_s_setprio(1);
#pragma unroll
    for (int jf = 0; jf < 4; ++jf) {
      int j = jf * 16 + l15;
#pragma unroll
      for (int kf = 0; kf < 4; ++kf) {
        bf16x8 kfr = *(const bf16x8*)(&Ks[cur][j * 128 + (((kf * 4 + g) ^ (j & 7)) * 8)]);
        s[jf] = __builtin_amdgcn_mfma_f32_16x16x32_bf16(qf[kf], kfr, s[jf], 0, 0, 0);
      }
    }
    __builtin_amdgcn_s_setprio(0);

    // ---- online softmax, defer-max (THR=11.5 in log2 domain -> P <= ~2900)
#pragma unroll
    for (int r = 0; r < 4; ++r) {
      float mx = fmaxf(fmaxf(s[0][r], s[1][r]), fmaxf(s[2][r], s[3][r]));
#pragma unroll
      for (int msk = 1; msk < 16; msk <<= 1) mx = fmaxf(mx, __shfl_xor(mx, msk, 64));
      if (!__all(mx <= mrun[r] + 11.5f)) {
        float mnew = fmaxf(mrun[r], mx);
        float resc = __builtin_amdgcn_exp2f(mrun[r] - mnew);
        lrun[r] *= resc;
#pragma unroll
        for (int df = 0; df < 8; ++df) of[df][r] *= resc;
        mrun[r] = mnew;
      }
      float ps = 0.f;
      float pj[4];
#pragma unroll
      for (int jf = 0; jf < 4; ++jf) {
        pj[jf] = __builtin_amdgcn_exp2f(s[jf][r] - mrun[r]);
        ps += pj[jf];
      }
      lrun[r] += ps;   // lane-partial; no per-tile cross-lane reduce
#pragma unroll
      for (int jf = 0; jf < 4; ++jf)
        Ps[(w * 16 + g * 4 + r) * 72 + jf * 16 + l15] = f2bf(pj[jf]);
    }

    // ---- PV: O[q][d] += P[q][j] V[j][d]
    bf16x8 pa[2];
#pragma unroll
    for (int kf2 = 0; kf2 < 2; ++kf2)
      pa[kf2] = *(const bf16x8*)(&Ps[(w * 16 + l15) * 72 + kf2 * 32 + g * 8]);
    __builtin_amdgcn_s_setprio(1);
#pragma unroll
    for (int df = 0; df < 8; ++df) {
      int d = df * 16 + l15;
#pragma unroll
      for (int kf2 = 0; kf2 < 2; ++kf2) {
        bf16x8 vfr = *(const bf16x8*)(&Vs[cur][d * 64 + (((kf2 * 4 + g) ^ (d & 7)) * 8)]);
        of[df] = __builtin_amdgcn_mfma_f32_16x16x32_bf16(pa[kf2], vfr, of[df], 0, 0, 0);
      }
    }
    __builtin_amdgcn_s_setprio(0);
  }

  // ---- epilogue: reduce lane-partial l across the 16 j-lanes, O /= l
  float inv[4];
#pragma unroll
  for (int r = 0; r < 4; ++r) {
    float ps = lrun[r];
#pragma unroll
    for (int msk = 1; msk < 16; msk <<= 1) ps += __shfl_xor(ps, msk, 64);
    inv[r] = 1.0f / ps;
  }
  unsigned short* Og = O + ((size_t)(b * 2048 + q0 + w * 16)) * 1024 + h * 128;
#pragma unroll
  for (int df = 0; df < 8; ++df)
#pragma unroll
    for (int r = 0; r < 4; ++r)
      Og[(size_t)(g * 4 + r) * 1024 + df * 16 + l15] = f2bf(of[df][r] * inv[r]);
}

// ---------------------------------------------------------------------------
// Host side
// ---------------------------------------------------------------------------
extern "C" void kernel_launch(void* const* d_in, const int* in_sizes, int n_in,
                              void* d_out, int out_size, void* d_ws, size_t ws_size,
                              hipStream_t stream) {
  const float* x    = (const float*)d_in[0];
  const float* cond = (const float*)d_in[1];
  const float* Wq   = (const float*)d_in[2];
  const float* Wk   = (const float*)d_in[3];
  const float* Wv   = (const float*)d_in[4];
  const float* Wo   = (const float*)d_in[5];
  const float* bo   = (const float*)d_in[6];

  char* p = (char*)d_ws;
  unsigned short* xb  = (unsigned short*)(p + 0);          // 16 MB  x bf16
  unsigned short* cb  = (unsigned short*)(p + 16777216);   // 16 MB  cond bf16
  unsigned short* Wqt = (unsigned short*)(p + 33554432);   // 2 MB   [N][K]
  unsigned short* Wkt = (unsigned short*)(p + 35651584);
  unsigned short* Wvt = (unsigned short*)(p + 37748736);
  unsigned short* Wot = (unsigned short*)(p + 39845888);
  unsigned short* Qb  = (unsigned short*)(p + 41943040);   // 16 MB [8192][1024]
  unsigned short* Kb  = (unsigned short*)(p + 58720256);   // 16 MB
  unsigned short* Vtb = (unsigned short*)(p + 75497472);   // 16 MB [32][128][2048]
  unsigned short* Ab  = (unsigned short*)(p + 92274688);   // 16 MB attn out
  (void)in_sizes; (void)n_in; (void)out_size; (void)ws_size;

  // converts
  convert_f32_bf16<<<2048, 256, 0, stream>>>(x, xb, 8388608 / 4);
  convert_f32_bf16<<<2048, 256, 0, stream>>>(cond, cb, 8388608 / 4);
  tconv<<<dim3(32, 32), dim3(32, 8), 0, stream>>>(Wq, Wqt, 1024, 1024);
  tconv<<<dim3(32, 32), dim3(32, 8), 0, stream>>>(Wk, Wkt, 1024, 1024);
  tconv<<<dim3(32, 32), dim3(32, 8), 0, stream>>>(Wv, Wvt, 1024, 1024);
  tconv<<<dim3(32, 32), dim3(32, 8), 0, stream>>>(Wo, Wot, 1024, 1024);

  const float QSCALE = 0.125f * 1.44269504f;   // folded into Q projection

  // projections
  gemm_bt<0><<<dim3(8, 64), 256, 0, stream>>>(xb, Wqt, Qb, nullptr, 8192, 1024, 1024, QSCALE);
  gemm_bt<0><<<dim3(8, 64), 256, 0, stream>>>(cb, Wkt, Kb, nullptr, 8192, 1024, 1024, 1.0f);
  // V transposed at source: Vt[i=h*128+d][c=b*2048+j] = Wvt[i,:] . cb[c,:]
  gemm_bt<2><<<dim3(64, 8), 256, 0, stream>>>(Wvt, cb, Vtb, nullptr, 1024, 8192, 1024, 1.0f);

  // flash attention: grid (Nq/128, B*H)
  attn_kernel<<<dim3(16, 32), 512, 0, stream>>>(Qb, Kb, Vtb, Ab);

  // output projection + bias, f32 out
  gemm_bt<1><<<dim3(8, 64), 256, 0, stream>>>(Ab, Wot, (float*)d_out, bo, 8192, 1024, 1024, 1.0f);
}

// Round 5
// 329.014 us; speedup vs baseline: 1.3519x; 1.2101x over previous
//
#include <hip/hip_runtime.h>
#include <cstdint>
#include <cstddef>

// ---------------------------------------------------------------------------
// CrossAttention on MI355X (gfx950), v4.
// v3 -> v4: attn LDS 146->80 KB (ring-2 + swizzled P buffer) => 2 blocks/CU;
// ballot fast-path softmax max (no ds_bpermute in steady state); GEMM ring-2
// (32 KB LDS, ~3 blocks/CU); fused convert/tconv launches (11 -> 7 kernels).
// ---------------------------------------------------------------------------

typedef __attribute__((ext_vector_type(8))) __bf16 bf16x8;
typedef __attribute__((ext_vector_type(4))) float  f32x4;

__device__ __forceinline__ unsigned short f2bf(float f) {
  union { float f; unsigned u; } v; v.f = f;
  unsigned r = v.u + 0x7FFFu + ((v.u >> 16) & 1u);   // RNE
  return (unsigned short)(r >> 16);
}

__device__ __forceinline__ void async_copy16(const void* g, void* l) {
  __builtin_amdgcn_global_load_lds(
      (const __attribute__((address_space(1))) void*)g,
      (__attribute__((address_space(3))) void*)l, 16, 0, 0);
}

// tile-t-ready wait: own stage(t) loads are the only outstanding vmem here.
__device__ __forceinline__ void tile_ready_barrier() {
  __builtin_amdgcn_sched_barrier(0);
  asm volatile("s_waitcnt vmcnt(0)" ::: "memory");
  __builtin_amdgcn_s_barrier();
  __builtin_amdgcn_sched_barrier(0);
}

// ---------------------------------------------------------------------------
// f32 -> bf16 elementwise, both tensors in one launch (z selects)
// ---------------------------------------------------------------------------
__global__ void convert2_f32_bf16(const float* __restrict__ a,
                                  unsigned short* __restrict__ ao,
                                  const float* __restrict__ b,
                                  unsigned short* __restrict__ bo, int n4) {
  const float* in = blockIdx.z ? b : a;
  unsigned short* out = blockIdx.z ? bo : ao;
  int idx = blockIdx.x * blockDim.x + threadIdx.x;
  int stride = gridDim.x * blockDim.x;
  for (int i = idx; i < n4; i += stride) {
    float4 v = ((const float4*)in)[i];
    ushort4 o;
    o.x = f2bf(v.x); o.y = f2bf(v.y); o.z = f2bf(v.z); o.w = f2bf(v.w);
    ((ushort4*)out)[i] = o;
  }
}

// ---------------------------------------------------------------------------
// 4x weight transpose-convert in one launch: W [1024][1024] f32 -> Wt bf16
// ---------------------------------------------------------------------------
__global__ void tconv4(const float* __restrict__ W0, const float* __restrict__ W1,
                       const float* __restrict__ W2, const float* __restrict__ W3,
                       unsigned short* __restrict__ T0, unsigned short* __restrict__ T1,
                       unsigned short* __restrict__ T2, unsigned short* __restrict__ T3) {
  const int Kd = 1024, Nd = 1024;
  int z = blockIdx.z;
  const float* W = (z == 0) ? W0 : (z == 1) ? W1 : (z == 2) ? W2 : W3;
  unsigned short* Wt = (z == 0) ? T0 : (z == 1) ? T1 : (z == 2) ? T2 : T3;
  __shared__ float t[32][33];
  int tx = threadIdx.x, ty = threadIdx.y;  // 32 x 8
  int n0 = blockIdx.x * 32, k0 = blockIdx.y * 32;
#pragma unroll
  for (int i = 0; i < 4; ++i)
    t[ty + i * 8][tx] = W[(size_t)(k0 + ty + i * 8) * Nd + n0 + tx];
  __syncthreads();
#pragma unroll
  for (int i = 0; i < 4; ++i)
    Wt[(size_t)(n0 + ty + i * 8) * Kd + k0 + tx] = f2bf(t[tx][ty + i * 8]);
}

// ---------------------------------------------------------------------------
// GEMM: C[M,N] = A[M,K] * Bt[N,K]^T. 128x128 tile, BK=32, 4 waves,
// ring-2 staging (32 KB LDS -> ~3 blocks/CU), distance-1 prefetch,
// XCD-chunked swizzle (T1).
// MODE 0: C bf16 [M][N] scaled; MODE 1: C f32 + bias; MODE 2: Vt scatter.
// ---------------------------------------------------------------------------
template <int MODE>
__global__ __launch_bounds__(256, 3) void gemm_bt(
    const unsigned short* __restrict__ A, const unsigned short* __restrict__ Bt,
    void* __restrict__ Cp, const float* __restrict__ bias, int M, int N, int Kd,
    float oscale) {
  __shared__ __align__(16) unsigned short As[2][128 * 32];
  __shared__ __align__(16) unsigned short Bs[2][128 * 32];
  int tid = threadIdx.x, lane = tid & 63, wid = tid >> 6;
  int wm = wid >> 1, wn = wid & 1;
  int nwg = gridDim.x * gridDim.y;
  int wg = blockIdx.y * gridDim.x + blockIdx.x;
  int cpx = nwg >> 3;
  int sw = (wg & 7) * cpx + (wg >> 3);
  int bx = sw % gridDim.x, by = sw / gridDim.x;
  int m0 = by * 128, n0 = bx * 128;
  int l15 = lane & 15, g = lane >> 4;
  const unsigned short* Ag = A + (size_t)m0 * Kd;
  const unsigned short* Bg = Bt + (size_t)n0 * Kd;
  f32x4 acc[4][4] = {};

  auto stage = [&](int buf, int k0) {   // 4 loads/thread
#pragma unroll
    for (int it = 0; it < 2; ++it) {
      int c = it * 256 + tid;       // 512 chunks of 16B per tile
      int row = c >> 2, kg = c & 3; // [128 rows][4 chunks]
      async_copy16(Ag + (size_t)row * Kd + k0 + kg * 8, &As[buf][c * 8]);
      async_copy16(Bg + (size_t)row * Kd + k0 + kg * 8, &Bs[buf][c * 8]);
    }
  };

  const int NT = Kd >> 5;           // 32
  stage(0, 0);

  for (int t = 0; t < NT; ++t) {
    tile_ready_barrier();                     // tile t visible; buf (t+1)&1 free
    if (t + 1 < NT) stage((t + 1) & 1, (t + 1) * 32);
    int cur = t & 1;
    bf16x8 af[4], bfr[4];
#pragma unroll
    for (int i = 0; i < 4; ++i) {
      af[i]  = *(const bf16x8*)(&As[cur][(wm * 64 + i * 16 + l15) * 32 + g * 8]);
      bfr[i] = *(const bf16x8*)(&Bs[cur][(wn * 64 + i * 16 + l15) * 32 + g * 8]);
    }
    __builtin_amdgcn_s_setprio(1);
#pragma unroll
    for (int i = 0; i < 4; ++i)
#pragma unroll
      for (int j = 0; j < 4; ++j)
        acc[i][j] = __builtin_amdgcn_mfma_f32_16x16x32_bf16(af[i], bfr[j], acc[i][j], 0, 0, 0);
    __builtin_amdgcn_s_setprio(0);
  }

  // Epilogue. D layout: col = lane&15, row = (lane>>4)*4 + r
#pragma unroll
  for (int i = 0; i < 4; ++i) {
#pragma unroll
    for (int j = 0; j < 4; ++j) {
#pragma unroll
      for (int r = 0; r < 4; ++r) {
        int row = m0 + wm * 64 + i * 16 + g * 4 + r;
        int col = n0 + wn * 64 + j * 16 + l15;
        float v = acc[i][j][r];
        if (MODE == 0) {
          ((unsigned short*)Cp)[(size_t)row * N + col] = f2bf(v * oscale);
        } else if (MODE == 1) {
          ((float*)Cp)[(size_t)row * N + col] = v + bias[col];
        } else {
          size_t off = ((size_t)((col >> 11) * 8 + (row >> 7)) << 18) +
                       (size_t)(row & 127) * 2048 + (size_t)(col & 2047);
          ((unsigned short*)Cp)[off] = f2bf(v);
        }
      }
    }
  }
}

// ---------------------------------------------------------------------------
// Flash attention v4. 512 thr (8 waves), QBLK=128, KVB=64, ring-2 K/V
// (distance-1 prefetch), LDS exactly 80 KB -> 2 blocks/CU; ballot fast-path
// max (no shuffle reduce in steady state); XOR-swizzled K/V/P tiles;
// defer-max; Q pre-scaled (exp2 domain).
// ---------------------------------------------------------------------------
#define KVB 64
#define NKV 2048

__global__ __launch_bounds__(512, 4) void attn_kernel(
    const unsigned short* __restrict__ Q, const unsigned short* __restrict__ K,
    const unsigned short* __restrict__ Vt, unsigned short* __restrict__ O) {
  __shared__ __align__(16) unsigned short Ks[2][KVB * 128];   // 32 KB
  __shared__ __align__(16) unsigned short Vs[2][128 * KVB];   // 32 KB
  __shared__ __align__(16) unsigned short Ps[8 * 16 * 64];    // 16 KB, swizzled

  int tid = threadIdx.x, lane = tid & 63, w = tid >> 6;
  int l15 = lane & 15, g = lane >> 4;
  // XCD-chunked swizzle: 4 consecutive bh per XCD -> KV L2-resident
  int wgl = blockIdx.y * gridDim.x + blockIdx.x;   // 0..511
  int sw = (wgl & 7) * 64 + (wgl >> 3);
  int bh = sw >> 4, b = bh >> 3, h = bh & 7;
  int q0 = (sw & 15) * 128;

  const unsigned short* Qg = Q + ((size_t)(b * 2048 + q0 + w * 16)) * 1024 + h * 128;
  const unsigned short* Kg = K + ((size_t)(b * 2048)) * 1024 + h * 128;
  const unsigned short* Vg = Vt + (size_t)bh * (128 * 2048);

  // Q fragments in registers (Q pre-scaled by 0.125*log2e)
  bf16x8 qf[4];
#pragma unroll
  for (int kf = 0; kf < 4; ++kf)
    qf[kf] = *(const bf16x8*)(Qg + (size_t)l15 * 1024 + kf * 32 + g * 8);

  f32x4 of[8] = {};          // O acc: [df][r], q = g*4+r, d = df*16+l15
  float mrun[4], lrun[4];    // lrun lane-partial (reduced at epilogue)
#pragma unroll
  for (int r = 0; r < 4; ++r) { mrun[r] = -1e30f; lrun[r] = 0.f; }

  auto stage = [&](int buf, int j0) {   // 4 loads/thread
#pragma unroll
    for (int it = 0; it < 2; ++it) {          // K tile: 1024 chunks
      int c = it * 512 + tid;
      int row = c >> 4, kc = c & 15;
      async_copy16(Kg + (size_t)(j0 + row) * 1024 + ((kc ^ (row & 7)) * 8),
                   &Ks[buf][c * 8]);
    }
#pragma unroll
    for (int it = 0; it < 2; ++it) {          // V tile: 1024 chunks
      int c = it * 512 + tid;
      int row = c >> 3, jc = c & 7;
      async_copy16(Vg + (size_t)row * 2048 + j0 + ((jc ^ (row & 7)) * 8),
                   &Vs[buf][c * 8]);
    }
  };

  const int NT = NKV / KVB;   // 32
  stage(0, 0);

  for (int t = 0; t < NT; ++t) {
    tile_ready_barrier();                     // tile t visible; other buf free
    if (t + 1 < NT) stage((t + 1) & 1, (t + 1) * KVB);
    int cur = t & 1;

    // ---- S = Q K^T : s[jf] covers j = jf*16 + l15, q = g*4+r (exp2 domain)
    f32x4 s[4] = {};
    __builtin_amdgcn_s_setprio(1);
#pragma unroll
    for (int jf = 0; jf < 4; ++jf) {
      int j = jf * 16 + l15;
#pragma unroll
      for (int kf = 0; kf < 4; ++kf) {
        bf16x8 kfr = *(const bf16x8*)(&Ks[cur][j * 128 + (((kf * 4 + g) ^ (j & 7)) * 8)]);
        s[jf] = __builtin_amdgcn_mfma_f32_16x16x32_bf16(qf[kf], kfr, s[jf], 0, 0, 0);
      }
    }
    __builtin_amdgcn_s_setprio(0);

    // ---- online softmax: lane-local max + ballot fast path (THR=11.5 log2)
#pragma unroll
    for (int r = 0; r < 4; ++r) {
      float mxl = fmaxf(fmaxf(s[0][r], s[1][r]), fmaxf(s[2][r], s[3][r]));
      if (!__all(mxl <= mrun[r] + 11.5f)) {       // rare: first tile / outlier
        float mx = mxl;
#pragma unroll
        for (int msk = 1; msk < 16; msk <<= 1) mx = fmaxf(mx, __shfl_xor(mx, msk, 64));
        float mnew = fmaxf(mrun[r], mx);
        float resc = __builtin_amdgcn_exp2f(mrun[r] - mnew);
        lrun[r] *= resc;
#pragma unroll
        for (int df = 0; df < 8; ++df) of[df][r] *= resc;
        mrun[r] = mnew;
      }
      float ps = 0.f;
      float pj[4];
#pragma unroll
      for (int jf = 0; jf < 4; ++jf) {
        pj[jf] = __builtin_amdgcn_exp2f(s[jf][r] - mrun[r]);
        ps += pj[jf];
      }
      lrun[r] += ps;   // lane-partial
      // P write, chunk-swizzled: row = g*4+r, col = jf*16+l15
      int prow = g * 4 + r;
#pragma unroll
      for (int jf = 0; jf < 4; ++jf) {
        int idx = (w * 16 + prow) * 64 +
                  (((jf * 2 + (l15 >> 3)) ^ (prow & 7)) << 3) + (l15 & 7);
        Ps[idx] = f2bf(pj[jf]);
      }
    }

    // ---- PV: O[q][d] += P[q][j] V[j][d]
    bf16x8 pa[2];
#pragma unroll
    for (int kf2 = 0; kf2 < 2; ++kf2)
      pa[kf2] = *(const bf16x8*)(&Ps[(w * 16 + l15) * 64 + (((kf2 * 4 + g) ^ (l15 & 7)) << 3)]);
    __builtin_amdgcn_s_setprio(1);
#pragma unroll
    for (int df = 0; df < 8; ++df) {
      int d = df * 16 + l15;
#pragma unroll
      for (int kf2 = 0; kf2 < 2; ++kf2) {
        bf16x8 vfr = *(const bf16x8*)(&Vs[cur][d * 64 + (((kf2 * 4 + g) ^ (d & 7)) * 8)]);
        of[df] = __builtin_amdgcn_mfma_f32_16x16x32_bf16(pa[kf2], vfr, of[df], 0, 0, 0);
      }
    }
    __builtin_amdgcn_s_setprio(0);
  }

  // ---- epilogue: reduce lane-partial l across the 16 j-lanes, O /= l
  float inv[4];
#pragma unroll
  for (int r = 0; r < 4; ++r) {
    float ps = lrun[r];
#pragma unroll
    for (int msk = 1; msk < 16; msk <<= 1) ps += __shfl_xor(ps, msk, 64);
    inv[r] = 1.0f / ps;
  }
  unsigned short* Og = O + ((size_t)(b * 2048 + q0 + w * 16)) * 1024 + h * 128;
#pragma unroll
  for (int df = 0; df < 8; ++df)
#pragma unroll
    for (int r = 0; r < 4; ++r)
      Og[(size_t)(g * 4 + r) * 1024 + df * 16 + l15] = f2bf(of[df][r] * inv[r]);
}

// ---------------------------------------------------------------------------
// Host side
// ---------------------------------------------------------------------------
extern "C" void kernel_launch(void* const* d_in, const int* in_sizes, int n_in,
                              void* d_out, int out_size, void* d_ws, size_t ws_size,
                              hipStream_t stream) {
  const float* x    = (const float*)d_in[0];
  const float* cond = (const float*)d_in[1];
  const float* Wq   = (const float*)d_in[2];
  const float* Wk   = (const float*)d_in[3];
  const float* Wv   = (const float*)d_in[4];
  const float* Wo   = (const float*)d_in[5];
  const float* bo   = (const float*)d_in[6];

  char* p = (char*)d_ws;
  unsigned short* xb  = (unsigned short*)(p + 0);          // 16 MB  x bf16
  unsigned short* cb  = (unsigned short*)(p + 16777216);   // 16 MB  cond bf16
  unsigned short* Wqt = (unsigned short*)(p + 33554432);   // 2 MB   [N][K]
  unsigned short* Wkt = (unsigned short*)(p + 35651584);
  unsigned short* Wvt = (unsigned short*)(p + 37748736);
  unsigned short* Wot = (unsigned short*)(p + 39845888);
  unsigned short* Qb  = (unsigned short*)(p + 41943040);   // 16 MB [8192][1024]
  unsigned short* Kb  = (unsigned short*)(p + 58720256);   // 16 MB
  unsigned short* Vtb = (unsigned short*)(p + 75497472);   // 16 MB [32][128][2048]
  unsigned short* Ab  = (unsigned short*)(p + 92274688);   // 16 MB attn out
  (void)in_sizes; (void)n_in; (void)out_size; (void)ws_size;

  // fused converts (x + cond) and 4x weight transpose
  convert2_f32_bf16<<<dim3(1024, 1, 2), 256, 0, stream>>>(x, xb, cond, cb, 8388608 / 4);
  tconv4<<<dim3(32, 32, 4), dim3(32, 8), 0, stream>>>(Wq, Wk, Wv, Wo, Wqt, Wkt, Wvt, Wot);

  const float QSCALE = 0.125f * 1.44269504f;   // folded into Q projection

  // projections
  gemm_bt<0><<<dim3(8, 64), 256, 0, stream>>>(xb, Wqt, Qb, nullptr, 8192, 1024, 1024, QSCALE);
  gemm_bt<0><<<dim3(8, 64), 256, 0, stream>>>(cb, Wkt, Kb, nullptr, 8192, 1024, 1024, 1.0f);
  // V transposed at source: Vt[i=h*128+d][c=b*2048+j] = Wvt[i,:] . cb[c,:]
  gemm_bt<2><<<dim3(64, 8), 256, 0, stream>>>(Wvt, cb, Vtb, nullptr, 1024, 8192, 1024, 1.0f);

  // flash attention: grid (Nq/128, B*H)
  attn_kernel<<<dim3(16, 32), 512, 0, stream>>>(Qb, Kb, Vtb, Ab);

  // output projection + bias, f32 out
  gemm_bt<1><<<dim3(8, 64), 256, 0, stream>>>(Ab, Wot, (float*)d_out, bo, 8192, 1024, 1024, 1.0f);
}

// Round 6
// 313.775 us; speedup vs baseline: 1.4176x; 1.0486x over previous
//
#include <hip/hip_runtime.h>
#include <cstdint>
#include <cstddef>

// ---------------------------------------------------------------------------
// CrossAttention on MI355X (gfx950), v5.
// v4 -> v5: Q+K fused into one N=2048 GEMM (grid 1024 -> 4 blocks/CU);
// launch_bounds(256,4) on all GEMMs; XCD swizzle reoriented so each XCD's
// A/B working set is L2-resident; LDS chunk-XOR (both-sides) on GEMM tiles
// to cut ds_read_b128 conflicts. Attention identical to v4.
// ---------------------------------------------------------------------------

typedef __attribute__((ext_vector_type(8))) __bf16 bf16x8;
typedef __attribute__((ext_vector_type(4))) float  f32x4;

__device__ __forceinline__ unsigned short f2bf(float f) {
  union { float f; unsigned u; } v; v.f = f;
  unsigned r = v.u + 0x7FFFu + ((v.u >> 16) & 1u);   // RNE
  return (unsigned short)(r >> 16);
}

__device__ __forceinline__ void async_copy16(const void* g, void* l) {
  __builtin_amdgcn_global_load_lds(
      (const __attribute__((address_space(1))) void*)g,
      (__attribute__((address_space(3))) void*)l, 16, 0, 0);
}

__device__ __forceinline__ void tile_ready_barrier() {
  __builtin_amdgcn_sched_barrier(0);
  asm volatile("s_waitcnt vmcnt(0)" ::: "memory");
  __builtin_amdgcn_s_barrier();
  __builtin_amdgcn_sched_barrier(0);
}

// ---------------------------------------------------------------------------
// f32 -> bf16 elementwise, both tensors in one launch (z selects)
// ---------------------------------------------------------------------------
__global__ void convert2_f32_bf16(const float* __restrict__ a,
                                  unsigned short* __restrict__ ao,
                                  const float* __restrict__ b,
                                  unsigned short* __restrict__ bo, int n4) {
  const float* in = blockIdx.z ? b : a;
  unsigned short* out = blockIdx.z ? bo : ao;
  int idx = blockIdx.x * blockDim.x + threadIdx.x;
  int stride = gridDim.x * blockDim.x;
  for (int i = idx; i < n4; i += stride) {
    float4 v = ((const float4*)in)[i];
    ushort4 o;
    o.x = f2bf(v.x); o.y = f2bf(v.y); o.z = f2bf(v.z); o.w = f2bf(v.w);
    ((ushort4*)out)[i] = o;
  }
}

// ---------------------------------------------------------------------------
// 4x weight transpose-convert in one launch: W [1024][1024] f32 -> Wt bf16
// ---------------------------------------------------------------------------
__global__ void tconv4(const float* __restrict__ W0, const float* __restrict__ W1,
                       const float* __restrict__ W2, const float* __restrict__ W3,
                       unsigned short* __restrict__ T0, unsigned short* __restrict__ T1,
                       unsigned short* __restrict__ T2, unsigned short* __restrict__ T3) {
  const int Kd = 1024, Nd = 1024;
  int z = blockIdx.z;
  const float* W = (z == 0) ? W0 : (z == 1) ? W1 : (z == 2) ? W2 : W3;
  unsigned short* Wt = (z == 0) ? T0 : (z == 1) ? T1 : (z == 2) ? T2 : T3;
  __shared__ float t[32][33];
  int tx = threadIdx.x, ty = threadIdx.y;  // 32 x 8
  int n0 = blockIdx.x * 32, k0 = blockIdx.y * 32;
#pragma unroll
  for (int i = 0; i < 4; ++i)
    t[ty + i * 8][tx] = W[(size_t)(k0 + ty + i * 8) * Nd + n0 + tx];
  __syncthreads();
#pragma unroll
  for (int i = 0; i < 4; ++i)
    Wt[(size_t)(n0 + ty + i * 8) * Kd + k0 + tx] = f2bf(t[tx][ty + i * 8]);
}

// ---------------------------------------------------------------------------
// GEMM v5: C[M,N] = A[M,K] * Bt[N,K]^T, 128x128 tile, BK=32, 4 waves,
// ring-2 dist-1 prefetch, 4 blocks/CU, LDS chunk-XOR, L2-aware XCD swizzle.
// K fixed = 1024 (32 steps).
// MODE 0: QK-fused. A = (n0<1024 ? A0(xb) : A1(cb)); C: n<1024 -> Qb*qscale,
//         else Kb. grid(16, 64).
// MODE 1: O-proj. C f32 + bias. grid(8, 64).
// MODE 2: V swapped (A0 = Wvt, rows = inner dim; B = cb). C scattered to
//         Vt[32][128][2048]. grid(64, 8).
// ---------------------------------------------------------------------------
template <int MODE>
__global__ __launch_bounds__(256, 4) void gemm5(
    const unsigned short* __restrict__ A0, const unsigned short* __restrict__ A1,
    const unsigned short* __restrict__ Bt, void* __restrict__ C0,
    void* __restrict__ C1, const float* __restrict__ bias, float qscale) {
  const int Kd = 1024;
  __shared__ __align__(16) unsigned short As[2][128 * 32];
  __shared__ __align__(16) unsigned short Bs[2][128 * 32];
  int tid = threadIdx.x, lane = tid & 63, wid = tid >> 6;
  int wm = wid >> 1, wn = wid & 1;
  int l15 = lane & 15, g = lane >> 4;

  // XCD swizzle (wg&7 -> XCD). MODE 0/1: by-cluster per XCD (8 A-panels
  // resident), bx outer (B-panels swept once). MODE 2: bx-cluster (A=Wvt
  // 2MB resident + 8 cb-panels).
  int wg = blockIdx.y * gridDim.x + blockIdx.x;
  int x = wg & 7, i = wg >> 3;
  int bx, by;
  if (MODE == 2) { bx = x * 8 + (i >> 3); by = i & 7; }
  else           { bx = i >> 3;           by = x * 8 + (i & 7); }
  int m0 = by * 128, n0 = bx * 128;

  const unsigned short* Asrc = (MODE == 0 && n0 >= 1024) ? A1 : A0;
  const unsigned short* Ag = Asrc + (size_t)m0 * Kd;
  const unsigned short* Bg = Bt + (size_t)n0 * Kd;
  f32x4 acc[4][4] = {};

  // stage with chunk-XOR: LDS pos (row, p) holds global chunk p ^ ((row>>1)&3)
  auto stage = [&](int buf, int k0) {   // 4 loads/thread
#pragma unroll
    for (int it = 0; it < 2; ++it) {
      int c = it * 256 + tid;       // 512 chunks of 16B per tile
      int row = c >> 2, kg = c & 3; // [128 rows][4 chunks]
      int ks = kg ^ ((row >> 1) & 3);
      async_copy16(Ag + (size_t)row * Kd + k0 + ks * 8, &As[buf][c * 8]);
      async_copy16(Bg + (size_t)row * Kd + k0 + ks * 8, &Bs[buf][c * 8]);
    }
  };

  const int NT = Kd >> 5;           // 32
  stage(0, 0);

  int rsw = (g ^ ((l15 >> 1) & 3)) * 8;   // swizzled read chunk (shorts)
  for (int t = 0; t < NT; ++t) {
    tile_ready_barrier();                     // tile t visible; other buf free
    if (t + 1 < NT) stage((t + 1) & 1, (t + 1) * 32);
    int cur = t & 1;
    bf16x8 af[4], bfr[4];
#pragma unroll
    for (int ii = 0; ii < 4; ++ii) {
      af[ii]  = *(const bf16x8*)(&As[cur][(wm * 64 + ii * 16 + l15) * 32 + rsw]);
      bfr[ii] = *(const bf16x8*)(&Bs[cur][(wn * 64 + ii * 16 + l15) * 32 + rsw]);
    }
    __builtin_amdgcn_s_setprio(1);
#pragma unroll
    for (int ii = 0; ii < 4; ++ii)
#pragma unroll
      for (int jj = 0; jj < 4; ++jj)
        acc[ii][jj] = __builtin_amdgcn_mfma_f32_16x16x32_bf16(af[ii], bfr[jj], acc[ii][jj], 0, 0, 0);
    __builtin_amdgcn_s_setprio(0);
  }

  // Epilogue. D layout: col = lane&15, row = (lane>>4)*4 + r
#pragma unroll
  for (int ii = 0; ii < 4; ++ii) {
#pragma unroll
    for (int jj = 0; jj < 4; ++jj) {
#pragma unroll
      for (int r = 0; r < 4; ++r) {
        int row = m0 + wm * 64 + ii * 16 + g * 4 + r;
        int col = n0 + wn * 64 + jj * 16 + l15;
        float v = acc[ii][jj][r];
        if (MODE == 0) {
          if (n0 < 1024)
            ((unsigned short*)C0)[(size_t)row * 1024 + col] = f2bf(v * qscale);
          else
            ((unsigned short*)C1)[(size_t)row * 1024 + (col & 1023)] = f2bf(v);
        } else if (MODE == 1) {
          ((float*)C0)[(size_t)row * 1024 + col] = v + bias[col];
        } else {
          size_t off = ((size_t)((col >> 11) * 8 + (row >> 7)) << 18) +
                       (size_t)(row & 127) * 2048 + (size_t)(col & 2047);
          ((unsigned short*)C0)[off] = f2bf(v);
        }
      }
    }
  }
}

// ---------------------------------------------------------------------------
// Flash attention (identical to v4). 512 thr (8 waves), QBLK=128, KVB=64,
// ring-2 K/V dist-1 prefetch, 80 KB LDS -> 2 blocks/CU, ballot fast-path max,
// XOR-swizzled K/V/P tiles, defer-max, Q pre-scaled (exp2 domain).
// ---------------------------------------------------------------------------
#define KVB 64
#define NKV 2048

__global__ __launch_bounds__(512, 4) void attn_kernel(
    const unsigned short* __restrict__ Q, const unsigned short* __restrict__ K,
    const unsigned short* __restrict__ Vt, unsigned short* __restrict__ O) {
  __shared__ __align__(16) unsigned short Ks[2][KVB * 128];   // 32 KB
  __shared__ __align__(16) unsigned short Vs[2][128 * KVB];   // 32 KB
  __shared__ __align__(16) unsigned short Ps[8 * 16 * 64];    // 16 KB, swizzled

  int tid = threadIdx.x, lane = tid & 63, w = tid >> 6;
  int l15 = lane & 15, g = lane >> 4;
  int wgl = blockIdx.y * gridDim.x + blockIdx.x;   // 0..511
  int sw = (wgl & 7) * 64 + (wgl >> 3);
  int bh = sw >> 4, b = bh >> 3, h = bh & 7;
  int q0 = (sw & 15) * 128;

  const unsigned short* Qg = Q + ((size_t)(b * 2048 + q0 + w * 16)) * 1024 + h * 128;
  const unsigned short* Kg = K + ((size_t)(b * 2048)) * 1024 + h * 128;
  const unsigned short* Vg = Vt + (size_t)bh * (128 * 2048);

  bf16x8 qf[4];
#pragma unroll
  for (int kf = 0; kf < 4; ++kf)
    qf[kf] = *(const bf16x8*)(Qg + (size_t)l15 * 1024 + kf * 32 + g * 8);

  f32x4 of[8] = {};
  float mrun[4], lrun[4];
#pragma unroll
  for (int r = 0; r < 4; ++r) { mrun[r] = -1e30f; lrun[r] = 0.f; }

  auto stage = [&](int buf, int j0) {
#pragma unroll
    for (int it = 0; it < 2; ++it) {          // K tile
      int c = it * 512 + tid;
      int row = c >> 4, kc = c & 15;
      async_copy16(Kg + (size_t)(j0 + row) * 1024 + ((kc ^ (row & 7)) * 8),
                   &Ks[buf][c * 8]);
    }
#pragma unroll
    for (int it = 0; it < 2; ++it) {          // V tile
      int c = it * 512 + tid;
      int row = c >> 3, jc = c & 7;
      async_copy16(Vg + (size_t)row * 2048 + j0 + ((jc ^ (row & 7)) * 8),
                   &Vs[buf][c * 8]);
    }
  };

  const int NT = NKV / KVB;   // 32
  stage(0, 0);

  for (int t = 0; t < NT; ++t) {
    tile_ready_barrier();
    if (t + 1 < NT) stage((t + 1) & 1, (t + 1) * KVB);
    int cur = t & 1;

    f32x4 s[4] = {};
    __builtin_amdgcn_s_setprio(1);
#pragma unroll
    for (int jf = 0; jf < 4; ++jf) {
      int j = jf * 16 + l15;
#pragma unroll
      for (int kf = 0; kf < 4; ++kf) {
        bf16x8 kfr = *(const bf16x8*)(&Ks[cur][j * 128 + (((kf * 4 + g) ^ (j & 7)) * 8)]);
        s[jf] = __builtin_amdgcn_mfma_f32_16x16x32_bf16(qf[kf], kfr, s[jf], 0, 0, 0);
      }
    }
    __builtin_amdgcn_s_setprio(0);

#pragma unroll
    for (int r = 0; r < 4; ++r) {
      float mxl = fmaxf(fmaxf(s[0][r], s[1][r]), fmaxf(s[2][r], s[3][r]));
      if (!__all(mxl <= mrun[r] + 11.5f)) {
        float mx = mxl;
#pragma unroll
        for (int msk = 1; msk < 16; msk <<= 1) mx = fmaxf(mx, __shfl_xor(mx, msk, 64));
        float mnew = fmaxf(mrun[r], mx);
        float resc = __builtin_amdgcn_exp2f(mrun[r] - mnew);
        lrun[r] *= resc;
#pragma unroll
        for (int df = 0; df < 8; ++df) of[df][r] *= resc;
        mrun[r] = mnew;
      }
      float ps = 0.f;
      float pj[4];
#pragma unroll
      for (int jf = 0; jf < 4; ++jf) {
        pj[jf] = __builtin_amdgcn_exp2f(s[jf][r] - mrun[r]);
        ps += pj[jf];
      }
      lrun[r] += ps;
      int prow = g * 4 + r;
#pragma unroll
      for (int jf = 0; jf < 4; ++jf) {
        int idx = (w * 16 + prow) * 64 +
                  (((jf * 2 + (l15 >> 3)) ^ (prow & 7)) << 3) + (l15 & 7);
        Ps[idx] = f2bf(pj[jf]);
      }
    }

    bf16x8 pa[2];
#pragma unroll
    for (int kf2 = 0; kf2 < 2; ++kf2)
      pa[kf2] = *(const bf16x8*)(&Ps[(w * 16 + l15) * 64 + (((kf2 * 4 + g) ^ (l15 & 7)) << 3)]);
    __builtin_amdgcn_s_setprio(1);
#pragma unroll
    for (int df = 0; df < 8; ++df) {
      int d = df * 16 + l15;
#pragma unroll
      for (int kf2 = 0; kf2 < 2; ++kf2) {
        bf16x8 vfr = *(const bf16x8*)(&Vs[cur][d * 64 + (((kf2 * 4 + g) ^ (d & 7)) * 8)]);
        of[df] = __builtin_amdgcn_mfma_f32_16x16x32_bf16(pa[kf2], vfr, of[df], 0, 0, 0);
      }
    }
    __builtin_amdgcn_s_setprio(0);
  }

  float inv[4];
#pragma unroll
  for (int r = 0; r < 4; ++r) {
    float ps = lrun[r];
#pragma unroll
    for (int msk = 1; msk < 16; msk <<= 1) ps += __shfl_xor(ps, msk, 64);
    inv[r] = 1.0f / ps;
  }
  unsigned short* Og = O + ((size_t)(b * 2048 + q0 + w * 16)) * 1024 + h * 128;
#pragma unroll
  for (int df = 0; df < 8; ++df)
#pragma unroll
    for (int r = 0; r < 4; ++r)
      Og[(size_t)(g * 4 + r) * 1024 + df * 16 + l15] = f2bf(of[df][r] * inv[r]);
}

// ---------------------------------------------------------------------------
// Host side
// ---------------------------------------------------------------------------
extern "C" void kernel_launch(void* const* d_in, const int* in_sizes, int n_in,
                              void* d_out, int out_size, void* d_ws, size_t ws_size,
                              hipStream_t stream) {
  const float* x    = (const float*)d_in[0];
  const float* cond = (const float*)d_in[1];
  const float* Wq   = (const float*)d_in[2];
  const float* Wk   = (const float*)d_in[3];
  const float* Wv   = (const float*)d_in[4];
  const float* Wo   = (const float*)d_in[5];
  const float* bo   = (const float*)d_in[6];

  char* p = (char*)d_ws;
  unsigned short* xb  = (unsigned short*)(p + 0);          // 16 MB  x bf16
  unsigned short* cb  = (unsigned short*)(p + 16777216);   // 16 MB  cond bf16
  unsigned short* Wqt = (unsigned short*)(p + 33554432);   // 2 MB [N][K]; Wqt||Wkt contiguous
  unsigned short* Wkt = (unsigned short*)(p + 35651584);
  unsigned short* Wvt = (unsigned short*)(p + 37748736);
  unsigned short* Wot = (unsigned short*)(p + 39845888);
  unsigned short* Qb  = (unsigned short*)(p + 41943040);   // 16 MB [8192][1024]
  unsigned short* Kb  = (unsigned short*)(p + 58720256);   // 16 MB
  unsigned short* Vtb = (unsigned short*)(p + 75497472);   // 16 MB [32][128][2048]
  unsigned short* Ab  = (unsigned short*)(p + 92274688);   // 16 MB attn out
  (void)in_sizes; (void)n_in; (void)out_size; (void)ws_size;

  convert2_f32_bf16<<<dim3(1024, 1, 2), 256, 0, stream>>>(x, xb, cond, cb, 8388608 / 4);
  tconv4<<<dim3(32, 32, 4), dim3(32, 8), 0, stream>>>(Wq, Wk, Wv, Wo, Wqt, Wkt, Wvt, Wot);

  const float QSCALE = 0.125f * 1.44269504f;   // scale * log2(e), folded into Q

  // QK fused: N=2048 over Wqt||Wkt, A = xb (n<1024) / cb (n>=1024)
  gemm5<0><<<dim3(16, 64), 256, 0, stream>>>(xb, cb, Wqt, Qb, Kb, nullptr, QSCALE);
  // V swapped: Vt[i=h*128+d][c=b*2048+j] = Wvt[i,:] . cb[c,:]
  gemm5<2><<<dim3(64, 8), 256, 0, stream>>>(Wvt, nullptr, cb, Vtb, nullptr, nullptr, 1.0f);

  // flash attention: grid (Nq/128, B*H)
  attn_kernel<<<dim3(16, 32), 512, 0, stream>>>(Qb, Kb, Vtb, Ab);

  // output projection + bias, f32 out
  gemm5<1><<<dim3(8, 64), 256, 0, stream>>>(Ab, nullptr, Wot, (float*)d_out, nullptr, bo, 1.0f);
}